// Round 10
// baseline (296.793 us; speedup 1.0000x reference)
//
#include <hip/hip_runtime.h>
#include <hip/hip_bf16.h>
#include <math.h>

#define NB 256
#define SS 512
#define LL 128

typedef short bf16x8 __attribute__((ext_vector_type(8)));
typedef float f32x4 __attribute__((ext_vector_type(4)));

__device__ __forceinline__ short f2bf(float f) {
    __hip_bfloat16 h = __float2bfloat16(f);
    short s;
    __builtin_memcpy(&s, &h, 2);
    return s;
}
__device__ __forceinline__ float bf2f(short s) {
    return __int_as_float(((int)(unsigned short)s) << 16);
}

#define MFMA1632(c, a, bb) \
    c = __builtin_amdgcn_mfma_f32_16x16x32_bf16(a, bb, c, 0, 0, 0)

// Barrier WITHOUT vmcnt drain: LDS ops are lgkm-drained, then waves sync.
// Global feature prefetches stay in flight across it.
__device__ __forceinline__ void wave_barrier() {
    asm volatile("s_waitcnt lgkmcnt(0)" ::: "memory");
    __builtin_amdgcn_s_barrier();
}

// One BLOCK = 4 waves = TWO same-direction chains (batches b0,b1) in a
// ping-pong schedule; grid 256 -> 1 block/CU, 2 chains/CU (same as round 7)
// but the barrier idle of one chain is deterministically filled by the other
// chain's compute phase:
//   barrier -> read imgA | publish imgB | MFMA+epi A | pack pkA
//   barrier -> read imgB | publish imgA'| MFMA+epi B | pack pkB
// The two chains SHARE the exp(T) A-fragments (same direction), so VGPR
// stays ~130 (round 2's duplication trap avoided). Per-chain arithmetic is
// bit-identical to round 7 (ring, rescale, tree-MFMA). No setprio (1
// wave/SIMD). Hazards: every img/ring slot reuse is separated by >=2
// lgkm-draining barriers.
template <int ISB>
__device__ __forceinline__ void run_pair(
    const int w, const int lane,
    const float* __restrict__ fb0,      // batch b0 features (S,L)
    const float* __restrict__ fb1,      // batch b1 features (S,L)
    const float* __restrict__ start_t,
    const float* __restrict__ end_t,
    const float* __restrict__ trans,
    short* __restrict__ imgA,           // LDS [2][LL]
    short* __restrict__ imgB,           // LDS [2][LL]
    float* __restrict__ ringA,          // LDS [4][LL]
    float* __restrict__ ringB,          // LDS [4][LL]
    const int* __restrict__ lmA,        // LDS [SS]
    const int* __restrict__ lmB,        // LDS [SS]
    float* __restrict__ outv,           // av or bv base (NB*LL)
    float* __restrict__ oute,           // eFa/eBa base (NB)
    const int b0, const int b1)
{
    const int lo = lane & 15;
    const int hi = lane >> 4;
    const int nt0 = 2 * w, nt1 = 2 * w + 1;

    // ---- shared A-fragments (slot (hi,j) <-> k=32kt+8hi+j, row n=16nt+lo) ----
    bf16x8 Af0[4], Af1[4];
#pragma unroll
    for (int kt = 0; kt < 4; ++kt) {
        bf16x8 f0, f1;
        const int n0 = 16 * nt0 + lo, n1 = 16 * nt1 + lo;
#pragma unroll
        for (int j = 0; j < 8; ++j) {
            const int k = 32 * kt + 8 * hi + j;
            f0[j] = f2bf(__expf(ISB ? trans[n0 * LL + k] : trans[k * LL + n0]));
            f1[j] = f2bf(__expf(ISB ? trans[n1 * LL + k] : trans[k * LL + n1]));
        }
        Af0[kt] = f0;
        Af1[kt] = f1;
    }

    // ---- states (D layout: v[n2][j] = row 16*(2w+n2)+4hi+j) ----
    float vA[2][4], vB[2][4];
#pragma unroll
    for (int n2 = 0; n2 < 2; ++n2)
#pragma unroll
        for (int j = 0; j < 4; ++j) {
            const int p = 16 * (2 * w + n2) + 4 * hi + j;
            vA[n2][j] = ISB ? __expf(end_t[p]) : __expf(start_t[p] + fb0[p]);
            vB[n2][j] = ISB ? __expf(end_t[p]) : __expf(start_t[p] + fb1[p]);
        }

    // ---- round-0 publish packs ----
    short4 pkA0, pkA1, pkB0, pkB1;
    {
        f32x4 eA0 = {1.f, 1.f, 1.f, 1.f}, eA1 = eA0, eB0 = eA0, eB1 = eA0;
        if (ISB) {
#pragma unroll
            for (int j = 0; j < 4; ++j) {
                eA0[j] = __expf(fb0[(size_t)511 * LL + 16 * nt0 + 4 * hi + j]);
                eA1[j] = __expf(fb0[(size_t)511 * LL + 16 * nt1 + 4 * hi + j]);
                eB0[j] = __expf(fb1[(size_t)511 * LL + 16 * nt0 + 4 * hi + j]);
                eB1[j] = __expf(fb1[(size_t)511 * LL + 16 * nt1 + 4 * hi + j]);
            }
        }
        pkA0.x = f2bf(vA[0][0] * eA0[0]); pkA0.y = f2bf(vA[0][1] * eA0[1]);
        pkA0.z = f2bf(vA[0][2] * eA0[2]); pkA0.w = f2bf(vA[0][3] * eA0[3]);
        pkA1.x = f2bf(vA[1][0] * eA1[0]); pkA1.y = f2bf(vA[1][1] * eA1[1]);
        pkA1.z = f2bf(vA[1][2] * eA1[2]); pkA1.w = f2bf(vA[1][3] * eA1[3]);
        pkB0.x = f2bf(vB[0][0] * eB0[0]); pkB0.y = f2bf(vB[0][1] * eB0[1]);
        pkB0.z = f2bf(vB[0][2] * eB0[2]); pkB0.w = f2bf(vB[0][3] * eB0[3]);
        pkB1.x = f2bf(vB[1][0] * eB1[0]); pkB1.y = f2bf(vB[1][1] * eB1[1]);
        pkB1.z = f2bf(vB[1][2] * eB1[2]); pkB1.w = f2bf(vB[1][3] * eB1[3]);
    }

    // ---- prologue: publish imgA[0] (visible at iter-0 barrier 1) ----
    if (lo == 0) {
        *(short4*)(imgA + 32 * w + 4 * hi) = pkA0;
        *(short4*)(imgA + 32 * w + 16 + 4 * hi) = pkA1;
    }

    // ---- ring duty prime: first duty at iter w serves round w+2 ----
    float2 nxtA, nxtB;
    {
        const int row = ISB ? (508 - w) : (w + 3);
        nxtA = *(const float2*)(fb0 + (size_t)row * LL + 2 * lane);
        nxtB = *(const float2*)(fb1 + (size_t)row * LL + 2 * lane);
    }

    int eaccA = 0, eaccB = 0;

    for (int r = 0; r < 256; ++r) {
        // ================= phase A =================
        wave_barrier();                      // imgA[r&1] visible
        const short* ibA = imgA + (r & 1) * LL;
        bf16x8 Bf[4];
#pragma unroll
        for (int kt = 0; kt < 4; ++kt)
            Bf[kt] = *(const bf16x8*)(ibA + 32 * kt + 8 * hi);
        // publish imgB[r&1] (read at this iter's phase B barrier)
        {
            short* ob = imgB + (r & 1) * LL;
            if (lo == 0) {
                *(short4*)(ob + 32 * w + 4 * hi) = pkB0;
                *(short4*)(ob + 32 * w + 16 + 4 * hi) = pkB1;
            }
        }
        const float* rpA = ringA + (r & 3) * LL + 4 * hi;
        f32x4 ecA0 = *(const f32x4*)(rpA + 16 * nt0);
        f32x4 ecA1 = *(const f32x4*)(rpA + 16 * nt1);
        if (w == (r & 3)) {                  // ring-A duty for round r+2
            *(float2*)(ringA + ((r + 2) & 3) * LL + 2 * lane) =
                make_float2(__expf(nxtA.x), __expf(nxtA.y));
            const int rowN = ISB ? (504 - r) : (r + 7);
            nxtA = *(const float2*)(fb0 + (size_t)rowN * LL + 2 * lane);
        }
        int mtA = lmA[ISB ? (511 - r) : (r + 1)];
        if (!ISB && r == 255) mtA = 0;

        {
            f32x4 c0a = {0.f, 0.f, 0.f, 0.f}, c0b = c0a, c1a = c0a, c1b = c0a;
            MFMA1632(c0a, Af0[0], Bf[0]);
            MFMA1632(c1a, Af1[0], Bf[0]);
            MFMA1632(c0b, Af0[2], Bf[2]);
            MFMA1632(c1b, Af1[2], Bf[2]);
            MFMA1632(c0a, Af0[1], Bf[1]);
            MFMA1632(c1a, Af1[1], Bf[1]);
            MFMA1632(c0b, Af0[3], Bf[3]);
            MFMA1632(c1b, Af1[3], Bf[3]);
            const f32x4 cc0 = c0a + c0b;
            const f32x4 cc1 = c1a + c1b;
#pragma unroll
            for (int j = 0; j < 4; ++j) {
                const float c0 = ISB ? cc0[j] : ecA0[j] * cc0[j];
                const float c1 = ISB ? cc1[j] : ecA1[j] * cc1[j];
                vA[0][j] = mtA ? c0 : vA[0][j];
                vA[1][j] = mtA ? c1 : vA[1][j];
            }
        }
        if ((r & 7) == 7) {                  // rescale A (image-derived, exact)
            float s = 0.f;
#pragma unroll
            for (int kt = 0; kt < 4; ++kt)
#pragma unroll
                for (int j = 0; j < 8; ++j) s += bf2f(Bf[kt][j]);
            s += __shfl_xor(s, 16);
            s += __shfl_xor(s, 32);
            int ex;
            frexpf(s, &ex);
#pragma unroll
            for (int n2 = 0; n2 < 2; ++n2)
#pragma unroll
                for (int j = 0; j < 4; ++j) vA[n2][j] = ldexpf(vA[n2][j], -ex);
            eaccA += ex;
        }
        // pack pkA for round r+1 (bwd folds this round's eft)
        pkA0.x = f2bf(ISB ? vA[0][0] * ecA0[0] : vA[0][0]);
        pkA0.y = f2bf(ISB ? vA[0][1] * ecA0[1] : vA[0][1]);
        pkA0.z = f2bf(ISB ? vA[0][2] * ecA0[2] : vA[0][2]);
        pkA0.w = f2bf(ISB ? vA[0][3] * ecA0[3] : vA[0][3]);
        pkA1.x = f2bf(ISB ? vA[1][0] * ecA1[0] : vA[1][0]);
        pkA1.y = f2bf(ISB ? vA[1][1] * ecA1[1] : vA[1][1]);
        pkA1.z = f2bf(ISB ? vA[1][2] * ecA1[2] : vA[1][2]);
        pkA1.w = f2bf(ISB ? vA[1][3] * ecA1[3] : vA[1][3]);

        // ================= phase B =================
        wave_barrier();                      // imgB[r&1] visible
        const short* ibB = imgB + (r & 1) * LL;
        bf16x8 Bg[4];
#pragma unroll
        for (int kt = 0; kt < 4; ++kt)
            Bg[kt] = *(const bf16x8*)(ibB + 32 * kt + 8 * hi);
        // publish imgA[(r+1)&1] (read at next iter's phase A barrier)
        {
            short* ob = imgA + ((r + 1) & 1) * LL;
            if (lo == 0) {
                *(short4*)(ob + 32 * w + 4 * hi) = pkA0;
                *(short4*)(ob + 32 * w + 16 + 4 * hi) = pkA1;
            }
        }
        const float* rpB = ringB + (r & 3) * LL + 4 * hi;
        f32x4 ecB0 = *(const f32x4*)(rpB + 16 * nt0);
        f32x4 ecB1 = *(const f32x4*)(rpB + 16 * nt1);
        if (w == (r & 3)) {                  // ring-B duty for round r+2
            *(float2*)(ringB + ((r + 2) & 3) * LL + 2 * lane) =
                make_float2(__expf(nxtB.x), __expf(nxtB.y));
            const int rowN = ISB ? (504 - r) : (r + 7);
            nxtB = *(const float2*)(fb1 + (size_t)rowN * LL + 2 * lane);
        }
        int mtB = lmB[ISB ? (511 - r) : (r + 1)];
        if (!ISB && r == 255) mtB = 0;

        {
            f32x4 c0a = {0.f, 0.f, 0.f, 0.f}, c0b = c0a, c1a = c0a, c1b = c0a;
            MFMA1632(c0a, Af0[0], Bg[0]);
            MFMA1632(c1a, Af1[0], Bg[0]);
            MFMA1632(c0b, Af0[2], Bg[2]);
            MFMA1632(c1b, Af1[2], Bg[2]);
            MFMA1632(c0a, Af0[1], Bg[1]);
            MFMA1632(c1a, Af1[1], Bg[1]);
            MFMA1632(c0b, Af0[3], Bg[3]);
            MFMA1632(c1b, Af1[3], Bg[3]);
            const f32x4 cc0 = c0a + c0b;
            const f32x4 cc1 = c1a + c1b;
#pragma unroll
            for (int j = 0; j < 4; ++j) {
                const float c0 = ISB ? cc0[j] : ecB0[j] * cc0[j];
                const float c1 = ISB ? cc1[j] : ecB1[j] * cc1[j];
                vB[0][j] = mtB ? c0 : vB[0][j];
                vB[1][j] = mtB ? c1 : vB[1][j];
            }
        }
        if ((r & 7) == 7) {                  // rescale B
            float s = 0.f;
#pragma unroll
            for (int kt = 0; kt < 4; ++kt)
#pragma unroll
                for (int j = 0; j < 8; ++j) s += bf2f(Bg[kt][j]);
            s += __shfl_xor(s, 16);
            s += __shfl_xor(s, 32);
            int ex;
            frexpf(s, &ex);
#pragma unroll
            for (int n2 = 0; n2 < 2; ++n2)
#pragma unroll
                for (int j = 0; j < 4; ++j) vB[n2][j] = ldexpf(vB[n2][j], -ex);
            eaccB += ex;
        }
        // pack pkB for round r+1
        pkB0.x = f2bf(ISB ? vB[0][0] * ecB0[0] : vB[0][0]);
        pkB0.y = f2bf(ISB ? vB[0][1] * ecB0[1] : vB[0][1]);
        pkB0.z = f2bf(ISB ? vB[0][2] * ecB0[2] : vB[0][2]);
        pkB0.w = f2bf(ISB ? vB[0][3] * ecB0[3] : vB[0][3]);
        pkB1.x = f2bf(ISB ? vB[1][0] * ecB1[0] : vB[1][0]);
        pkB1.y = f2bf(ISB ? vB[1][1] * ecB1[1] : vB[1][1]);
        pkB1.z = f2bf(ISB ? vB[1][2] * ecB1[2] : vB[1][2]);
        pkB1.w = f2bf(ISB ? vB[1][3] * ecB1[3] : vB[1][3]);
    }

    // ---- export (cols are replicas: lo==0 lanes write) ----
    if (lo == 0) {
        *(f32x4*)(outv + b0 * LL + 16 * nt0 + 4 * hi) =
            (f32x4){vA[0][0], vA[0][1], vA[0][2], vA[0][3]};
        *(f32x4*)(outv + b0 * LL + 16 * nt1 + 4 * hi) =
            (f32x4){vA[1][0], vA[1][1], vA[1][2], vA[1][3]};
        *(f32x4*)(outv + b1 * LL + 16 * nt0 + 4 * hi) =
            (f32x4){vB[0][0], vB[0][1], vB[0][2], vB[0][3]};
        *(f32x4*)(outv + b1 * LL + 16 * nt1 + 4 * hi) =
            (f32x4){vB[1][0], vB[1][1], vB[1][2], vB[1][3]};
    }
    if (w == 0 && lane == 0) {
        oute[b0] = (float)eaccA;
        oute[b1] = (float)eaccB;
    }
}

__global__ __launch_bounds__(256, 1) void crf_chain_kernel(
    const float* __restrict__ feats,    // (B,S,L)
    const float* __restrict__ start_t,  // (L)
    const float* __restrict__ end_t,    // (L)
    const float* __restrict__ trans,    // (L,L)
    const int* __restrict__ mask,       // (B,S)
    const int* __restrict__ labels,     // (B,S)
    float* __restrict__ ws)
{
    const int bid = blockIdx.x;
    const int isB = bid >> 7;           // 0 = fwd pair, 1 = bwd pair
    const int p = bid & 127;
    const int b0 = 2 * p, b1 = 2 * p + 1;
    const int tid = threadIdx.x;
    const int w = tid >> 6;
    const int lane = tid & 63;

    __shared__ __align__(16) short imgA[2 * LL];    // 512 B dbuf
    __shared__ __align__(16) short imgB[2 * LL];    // 512 B dbuf
    __shared__ __align__(16) float ringA[4 * LL];   // 2 KB
    __shared__ __align__(16) float ringB[4 * LL];   // 2 KB
    __shared__ int lmask2[2 * SS];                  // 4 KB
    __shared__ float nred[4];
    __shared__ int cred[4];

    const float* fb0 = feats + (size_t)b0 * SS * LL;
    const float* fb1 = feats + (size_t)b1 * SS * LL;

    // ---- cooperative fills (visible at the first in-loop barrier) ----
    lmask2[tid] = mask[b0 * SS + tid];
    lmask2[tid + 256] = mask[b0 * SS + tid + 256];
    lmask2[SS + tid] = mask[b1 * SS + tid];
    lmask2[SS + tid + 256] = mask[b1 * SS + tid + 256];
    {
        const int slot = tid >> 7;          // ring slots 0,1 = rounds 0,1
        const int e = tid & 127;
        const int row = isB ? (510 - slot) : (1 + slot);
        ringA[slot * LL + e] = __expf(fb0[(size_t)row * LL + e]);
        ringB[slot * LL + e] = __expf(fb1[(size_t)row * LL + e]);
    }

    float* av = ws;                      // alpha_255 (B,L)
    float* bv = ws + NB * LL;            // beta_255  (B,L)
    float* eFa = ws + 2 * NB * LL;       // fwd exponents (B)
    float* eBa = eFa + NB;               // bwd exponents (B)
    float* lognum = eBa + NB;            // numerator (B)

    if (isB)
        run_pair<1>(w, lane, fb0, fb1, start_t, end_t, trans, imgA, imgB,
                    ringA, ringB, lmask2, lmask2 + SS, bv, eBa, b0, b1);
    else
        run_pair<0>(w, lane, fb0, fb1, start_t, end_t, trans, imgA, imgB,
                    ringA, ringB, lmask2, lmask2 + SS, av, eFa, b0, b1);

    // ---- numerator (gold path, fp32 exact), bwd blocks: waves 0,1 -> b0,
    //      waves 2,3 -> b1; each wave reduces 256 positions ----
    if (isB) {
        const int bb = (w < 2) ? b0 : b1;
        const float* fbn = (w < 2) ? fb0 : fb1;
        const int* lb = labels + bb * SS;
        const int* mb = mask + bb * SS;
        float term = 0.f;
        int cnt = 0;
#pragma unroll
        for (int q = 0; q < 4; ++q) {
            const int tt = (w & 1) * 256 + lane + 64 * q;
            int l = lb[tt];
            if ((unsigned)l >= LL) l = 0;
            const int m = mb[tt];
            cnt += (m != 0);
            if (tt == 0) {
                term += start_t[l] + fbn[l];
            } else if (m) {
                int lp = lb[tt - 1];
                if ((unsigned)lp >= LL) lp = 0;
                term += trans[lp * LL + l] + fbn[(size_t)tt * LL + l];
            }
        }
#pragma unroll
        for (int o = 1; o < 64; o <<= 1) {
            term += __shfl_xor(term, o);
            cnt += __shfl_xor(cnt, o);
        }
        if (lane == 0) { nred[w] = term; cred[w] = cnt; }
        __syncthreads();
        if (tid == 0) {
            const float tot = nred[0] + nred[1];
            const int c = cred[0] + cred[1];
            int sl = c - 1;
            sl = sl < 0 ? 0 : (sl >= SS ? SS - 1 : sl);
            int lt = labels[b0 * SS + sl];
            if ((unsigned)lt >= LL) lt = 0;
            lognum[b0] = tot + end_t[lt];
        }
        if (tid == 128) {
            const float tot = nred[2] + nred[3];
            const int c = cred[2] + cred[3];
            int sl = c - 1;
            sl = sl < 0 ? 0 : (sl >= SS ? SS - 1 : sl);
            int lt = labels[b1 * SS + sl];
            if ((unsigned)lt >= LL) lt = 0;
            lognum[b1] = tot + end_t[lt];
        }
    }
}

// Combine: Z = sum_i alpha_255[i]*beta_255[i] * 2^(eF+eB); loss reduce.
__global__ __launch_bounds__(256) void crf_final_kernel(
    const float* __restrict__ ws, const float* __restrict__ conf,
    float* __restrict__ out)
{
    const int tid = threadIdx.x;  // = batch index
    const float* av = ws;
    const float* bv = ws + NB * LL;
    const float* eFa = ws + 2 * NB * LL;
    const float* eBa = eFa + NB;
    const float* ln = eBa + NB;

    const float4* a4 = (const float4*)(av + tid * LL);
    const float4* b4 = (const float4*)(bv + tid * LL);
    float dot = 0.f;
#pragma unroll 8
    for (int k = 0; k < 32; ++k) {
        float4 a = a4[k], bb = b4[k];
        dot += a.x * bb.x + a.y * bb.y + a.z * bb.z + a.w * bb.w;
    }
    float logZ = logf(dot) + 0.69314718055994531f * (eFa[tid] + eBa[tid]);
    float loss = (logZ - ln[tid]) * conf[tid] * (1.0f / NB);

#pragma unroll
    for (int o = 1; o < 64; o <<= 1) loss += __shfl_xor(loss, o);
    __shared__ float red[4];
    if ((tid & 63) == 0) red[tid >> 6] = loss;
    __syncthreads();
    if (tid == 0) out[0] = red[0] + red[1] + red[2] + red[3];
}

extern "C" void kernel_launch(void* const* d_in, const int* in_sizes, int n_in,
                              void* d_out, int out_size, void* d_ws, size_t ws_size,
                              hipStream_t stream) {
    const float* feats  = (const float*)d_in[0];
    const float* startt = (const float*)d_in[1];
    const float* endt   = (const float*)d_in[2];
    const float* trans  = (const float*)d_in[3];
    const float* conf   = (const float*)d_in[4];
    const int*   mask   = (const int*)d_in[5];
    const int*   labels = (const int*)d_in[6];
    float* out = (float*)d_out;
    float* ws = (float*)d_ws;  // needs (2*256*128 + 3*256) floats = ~266 KB

    hipLaunchKernelGGL(crf_chain_kernel, dim3(NB), dim3(256), 0, stream,
                       feats, startt, endt, trans, mask, labels, ws);
    hipLaunchKernelGGL(crf_final_kernel, dim3(1), dim3(256), 0, stream,
                       ws, conf, out);
}

// Round 11
// 206.835 us; speedup vs baseline: 1.4349x; 1.4349x over previous
//
#include <hip/hip_runtime.h>
#include <hip/hip_bf16.h>
#include <math.h>

#define NB 256
#define SS 512
#define LL 128

typedef short bf16x8 __attribute__((ext_vector_type(8)));
typedef float f32x4 __attribute__((ext_vector_type(4)));

__device__ __forceinline__ short f2bf(float f) {
    __hip_bfloat16 h = __float2bfloat16(f);
    short s;
    __builtin_memcpy(&s, &h, 2);
    return s;
}
__device__ __forceinline__ float bf2f(short s) {
    return __int_as_float(((int)(unsigned short)s) << 16);
}

#define MFMA1632(c, a, bb) \
    c = __builtin_amdgcn_mfma_f32_16x16x32_bf16(a, bb, c, 0, 0, 0)

// Barrier WITHOUT vmcnt drain: per-wave LDS ops (publishes + reads) are
// lgkm-drained, then the 4 waves sync. Global feature prefetches stay in
// flight across it.
__device__ __forceinline__ void wave_barrier() {
    asm volatile("s_waitcnt lgkmcnt(0)" ::: "memory");
    __builtin_amdgcn_s_barrier();
}

// CHAMPION STRUCTURE (round 7, restored): one BLOCK = 4 waves = one chain
// (fwd or bwd) of one batch; grid 512 -> 2 independent blocks/CU -> 2
// waves/SIMD from DIFFERENT chains, so one chain's barrier stall is filled
// by the other's issue (stochastic anti-phase). Wave w owns output tiles
// nt = 2w, 2w+1: 8 MFMAs + ~70 VALU per wave per round. State crosses waves
// through a 256-B dbuf LDS image (bf16); exp(T) A-frags live in VGPRs.
// Feature exp-ring: 4 slots, duty rotates over waves (wave r&3 serves round
// r+2), global prefetch deep. The post-barrier independent work (ring reads,
// duty, mask) deliberately stays AFTER the barrier where it fills ds_read/
// MFMA latency bubbles (hoisting it pre-barrier regressed: round 9).
// Rescale: every wave recomputes the same power-of-2 exponent from the
// shared image it already read (barrier-free, exact).
template <int ISB>
__device__ __forceinline__ void run_chain4(
    const int w, const int lane,
    const float* __restrict__ fb,       // this batch's features (S,L)
    const float* __restrict__ start_t,
    const float* __restrict__ end_t,
    const float* __restrict__ trans,
    short* __restrict__ img,            // LDS [2][LL]
    float* __restrict__ eRing,          // LDS [4][LL]
    const int* __restrict__ lmask,      // LDS [SS]
    float* __restrict__ outv,           // av/bv row (L floats)
    float* __restrict__ oute)           // eFa/eBa slot
{
    const int lo = lane & 15;
    const int hi = lane >> 4;
    const int nt0 = 2 * w, nt1 = 2 * w + 1;

    // ---- A-fragments for this wave's 2 output tiles (standard mapping:
    //      A slot (hi,j) of k-tile kt <-> k = 32kt+8hi+j, row n = 16nt+lo) ----
    // fwd: out[n] = sum_k expT[k][n] u[k];  bwd: out[i] = sum_j expT[i][j] u[j]
    bf16x8 Af0[4], Af1[4];
#pragma unroll
    for (int kt = 0; kt < 4; ++kt) {
        bf16x8 f0, f1;
        const int n0 = 16 * nt0 + lo, n1 = 16 * nt1 + lo;
#pragma unroll
        for (int j = 0; j < 8; ++j) {
            const int k = 32 * kt + 8 * hi + j;
            f0[j] = f2bf(__expf(ISB ? trans[n0 * LL + k] : trans[k * LL + n0]));
            f1[j] = f2bf(__expf(ISB ? trans[n1 * LL + k] : trans[k * LL + n1]));
        }
        Af0[kt] = f0;
        Af1[kt] = f1;
    }

    // ---- state init (D layout: v[n2][j] = row 16*(2w+n2)+4hi+j, cols repl.) ----
    float v[2][4];
#pragma unroll
    for (int n2 = 0; n2 < 2; ++n2)
#pragma unroll
        for (int j = 0; j < 4; ++j) {
            const int p = 16 * (2 * w + n2) + 4 * hi + j;
            v[n2][j] = ISB ? __expf(end_t[p]) : __expf(start_t[p] + fb[p]);
        }

    // ---- bwd: eft_prev prime = exp(f_511) at own positions ----
    f32x4 ep0 = {1.f, 1.f, 1.f, 1.f}, ep1 = ep0;
    if (ISB) {
#pragma unroll
        for (int j = 0; j < 4; ++j) {
            ep0[j] = __expf(fb[(size_t)511 * LL + 16 * nt0 + 4 * hi + j]);
            ep1[j] = __expf(fb[(size_t)511 * LL + 16 * nt1 + 4 * hi + j]);
        }
    }

    // ---- ring prefetch prime: this wave's first duty (round w) writes the
    //      eft row for round w+2: row = fwd w+3 / bwd 508-w ----
    float2 nxt;
    {
        const int row = ISB ? (508 - w) : (w + 3);
        nxt = *(const float2*)(fb + (size_t)row * LL + 2 * lane);
    }

    wave_barrier();   // ring slots 0/1 + lmask (cooperative fills) visible

    int eacc = 0;

    for (int r = 0; r < 256; ++r) {
        // ---- publish own 8 rows (pre-update state; bwd scaled by eft_prev) ----
        short4 p0, p1;
        p0.x = f2bf(ISB ? v[0][0] * ep0[0] : v[0][0]);
        p0.y = f2bf(ISB ? v[0][1] * ep0[1] : v[0][1]);
        p0.z = f2bf(ISB ? v[0][2] * ep0[2] : v[0][2]);
        p0.w = f2bf(ISB ? v[0][3] * ep0[3] : v[0][3]);
        p1.x = f2bf(ISB ? v[1][0] * ep1[0] : v[1][0]);
        p1.y = f2bf(ISB ? v[1][1] * ep1[1] : v[1][1]);
        p1.z = f2bf(ISB ? v[1][2] * ep1[2] : v[1][2]);
        p1.w = f2bf(ISB ? v[1][3] * ep1[3] : v[1][3]);
        short* ib = img + (r & 1) * LL;
        if (lo == 0) {
            *(short4*)(ib + 32 * w + 4 * hi) = p0;
            *(short4*)(ib + 32 * w + 16 + 4 * hi) = p1;
        }
        wave_barrier();  // publish complete + prior-round reads drained

        // ---- full image as B fragments (B slot (hi,j) <-> k=32kt+8hi+j) ----
        bf16x8 Bf[4];
#pragma unroll
        for (int kt = 0; kt < 4; ++kt)
            Bf[kt] = *(const bf16x8*)(ib + 32 * kt + 8 * hi);

        // ---- eft for this round (slot r&3, written 2 rounds ago) ----
        const float* rp = eRing + (r & 3) * LL + 4 * hi;
        f32x4 ec0 = *(const f32x4*)(rp + 16 * nt0);
        f32x4 ec1 = *(const f32x4*)(rp + 16 * nt1);

        // ---- ring duty (wave r&3): write slot for round r+2; prefetch ----
        if (w == (r & 3)) {
            *(float2*)(eRing + ((r + 2) & 3) * LL + 2 * lane) =
                make_float2(__expf(nxt.x), __expf(nxt.y));
            const int rowN = ISB ? (504 - r) : (r + 7);  // in [0,512) always
            nxt = *(const float2*)(fb + (size_t)rowN * LL + 2 * lane);
        }

        int mt = lmask[ISB ? (511 - r) : (r + 1)];
        if (!ISB && r == 255) mt = 0;  // fwd dummy round

        // ---- 8 MFMAs: 2 independent 4-deep accumulator chains ----
        f32x4 cc0 = {0.f, 0.f, 0.f, 0.f}, cc1 = {0.f, 0.f, 0.f, 0.f};
#pragma unroll
        for (int kt = 0; kt < 4; ++kt) {
            MFMA1632(cc0, Af0[kt], Bf[kt]);
            MFMA1632(cc1, Af1[kt], Bf[kt]);
        }

        // ---- epilogue: fwd cand = exp(f_t)*(T^T u); bwd cand = T*pub ----
#pragma unroll
        for (int j = 0; j < 4; ++j) {
            const float c0 = ISB ? cc0[j] : ec0[j] * cc0[j];
            const float c1 = ISB ? cc1[j] : ec1[j] * cc1[j];
            v[0][j] = mt ? c0 : v[0][j];
            v[1][j] = mt ? c1 : v[1][j];
        }

        // ---- rescale every 8 rounds: identical exponent on all waves,
        //      recomputed from the shared image (exact power of 2) ----
        if ((r & 7) == 7) {
            float s = 0.f;
#pragma unroll
            for (int kt = 0; kt < 4; ++kt)
#pragma unroll
                for (int j = 0; j < 8; ++j) s += bf2f(Bf[kt][j]);
            s += __shfl_xor(s, 16);   // combine hi groups (k-partition)
            s += __shfl_xor(s, 32);
            int ex;
            frexpf(s, &ex);
#pragma unroll
            for (int n2 = 0; n2 < 2; ++n2)
#pragma unroll
                for (int j = 0; j < 4; ++j) v[n2][j] = ldexpf(v[n2][j], -ex);
            eacc += ex;
        }

        if (ISB) { ep0 = ec0; ep1 = ec1; }  // eft_prev <- eft_cur
    }

    // ---- export own rows (cols are replicas: lo==0 lanes write) ----
    if (lo == 0) {
        *(f32x4*)(outv + 16 * nt0 + 4 * hi) =
            (f32x4){v[0][0], v[0][1], v[0][2], v[0][3]};
        *(f32x4*)(outv + 16 * nt1 + 4 * hi) =
            (f32x4){v[1][0], v[1][1], v[1][2], v[1][3]};
    }
    if (w == 0 && lane == 0) *oute = (float)eacc;
}

__global__ __launch_bounds__(256, 2) void crf_chain_kernel(
    const float* __restrict__ feats,    // (B,S,L)
    const float* __restrict__ start_t,  // (L)
    const float* __restrict__ end_t,    // (L)
    const float* __restrict__ trans,    // (L,L)
    const int* __restrict__ mask,       // (B,S)
    const int* __restrict__ labels,     // (B,S)
    float* __restrict__ ws)
{
    const int bid = blockIdx.x;
    const int b = bid & 255;
    const int isB = bid >> 8;   // 0 = forward chain, 1 = backward chain
    const int tid = threadIdx.x;
    const int w = tid >> 6;
    const int lane = tid & 63;

    __shared__ __align__(16) short img[2 * LL];     // 512 B, dbuf
    __shared__ __align__(16) float eRing[4 * LL];   // 2 KB
    __shared__ int lmask[SS];                       // 2 KB
    __shared__ float nred[4];
    __shared__ int cred[4];

    const float* fb = feats + (size_t)b * SS * LL;

    // ---- cooperative fills (visibility via the barrier inside run_chain4) ----
    lmask[tid] = mask[b * SS + tid];
    lmask[tid + 256] = mask[b * SS + tid + 256];
    {
        const int slot = tid >> 7;          // ring slots 0,1 = rounds 0,1
        const int e = tid & 127;
        const int row = isB ? (510 - slot) : (1 + slot);
        eRing[slot * LL + e] = __expf(fb[(size_t)row * LL + e]);
    }

    float* av = ws;                      // alpha_255 (B,L)
    float* bv = ws + NB * LL;            // beta_255  (B,L)
    float* eFa = ws + 2 * NB * LL;       // fwd exponents (B)
    float* eBa = eFa + NB;               // bwd exponents (B)
    float* lognum = eBa + NB;            // numerator (B)

    if (isB)
        run_chain4<1>(w, lane, fb, start_t, end_t, trans, img, eRing, lmask,
                      bv + b * LL, eBa + b);
    else
        run_chain4<0>(w, lane, fb, start_t, end_t, trans, img, eRing, lmask,
                      av + b * LL, eFa + b);

    // ---- numerator (gold path, fp32 exact), bwd blocks, 4 waves ----
    if (isB) {
        const int* lb = labels + b * SS;
        const int* mb = mask + b * SS;
        float term = 0.f;
        int cnt = 0;
#pragma unroll
        for (int q = 0; q < 2; ++q) {
            const int tt = tid + 256 * q;
            int l = lb[tt];
            if ((unsigned)l >= LL) l = 0;
            const int m = mb[tt];
            cnt += (m != 0);
            if (tt == 0) {
                term += start_t[l] + fb[l];
            } else if (m) {
                int lp = lb[tt - 1];
                if ((unsigned)lp >= LL) lp = 0;
                term += trans[lp * LL + l] + fb[(size_t)tt * LL + l];
            }
        }
#pragma unroll
        for (int o = 1; o < 64; o <<= 1) {
            term += __shfl_xor(term, o);
            cnt += __shfl_xor(cnt, o);
        }
        if (lane == 0) { nred[w] = term; cred[w] = cnt; }
        __syncthreads();
        if (tid == 0) {
            const float tot = nred[0] + nred[1] + nred[2] + nred[3];
            const int c = cred[0] + cred[1] + cred[2] + cred[3];
            int sl = c - 1;
            sl = sl < 0 ? 0 : (sl >= SS ? SS - 1 : sl);
            int lt = lb[sl];
            if ((unsigned)lt >= LL) lt = 0;
            lognum[b] = tot + end_t[lt];
        }
    }
}

// Combine: Z = sum_i alpha_255[i]*beta_255[i] * 2^(eF+eB); loss reduce.
__global__ __launch_bounds__(256) void crf_final_kernel(
    const float* __restrict__ ws, const float* __restrict__ conf,
    float* __restrict__ out)
{
    const int tid = threadIdx.x;  // = batch index
    const float* av = ws;
    const float* bv = ws + NB * LL;
    const float* eFa = ws + 2 * NB * LL;
    const float* eBa = eFa + NB;
    const float* ln = eBa + NB;

    const float4* a4 = (const float4*)(av + tid * LL);
    const float4* b4 = (const float4*)(bv + tid * LL);
    float dot = 0.f;
#pragma unroll 8
    for (int k = 0; k < 32; ++k) {
        float4 a = a4[k], bb = b4[k];
        dot += a.x * bb.x + a.y * bb.y + a.z * bb.z + a.w * bb.w;
    }
    float logZ = logf(dot) + 0.69314718055994531f * (eFa[tid] + eBa[tid]);
    float loss = (logZ - ln[tid]) * conf[tid] * (1.0f / NB);

#pragma unroll
    for (int o = 1; o < 64; o <<= 1) loss += __shfl_xor(loss, o);
    __shared__ float red[4];
    if ((tid & 63) == 0) red[tid >> 6] = loss;
    __syncthreads();
    if (tid == 0) out[0] = red[0] + red[1] + red[2] + red[3];
}

extern "C" void kernel_launch(void* const* d_in, const int* in_sizes, int n_in,
                              void* d_out, int out_size, void* d_ws, size_t ws_size,
                              hipStream_t stream) {
    const float* feats  = (const float*)d_in[0];
    const float* startt = (const float*)d_in[1];
    const float* endt   = (const float*)d_in[2];
    const float* trans  = (const float*)d_in[3];
    const float* conf   = (const float*)d_in[4];
    const int*   mask   = (const int*)d_in[5];
    const int*   labels = (const int*)d_in[6];
    float* out = (float*)d_out;
    float* ws = (float*)d_ws;  // needs (2*256*128 + 3*256) floats = ~266 KB

    hipLaunchKernelGGL(crf_chain_kernel, dim3(2 * NB), dim3(256), 0, stream,
                       feats, startt, endt, trans, mask, labels, ws);
    hipLaunchKernelGGL(crf_final_kernel, dim3(1), dim3(256), 0, stream,
                       ws, conf, out);
}

// Round 12
// 203.376 us; speedup vs baseline: 1.4593x; 1.0170x over previous
//
#include <hip/hip_runtime.h>
#include <hip/hip_bf16.h>
#include <math.h>

#define NB 256
#define SS 512
#define LL 128

typedef short bf16x8 __attribute__((ext_vector_type(8)));
typedef float f32x4 __attribute__((ext_vector_type(4)));

__device__ __forceinline__ short f2bf(float f) {
    __hip_bfloat16 h = __float2bfloat16(f);
    short s;
    __builtin_memcpy(&s, &h, 2);
    return s;
}
__device__ __forceinline__ float bf2f(short s) {
    return __int_as_float(((int)(unsigned short)s) << 16);
}

#define MFMA1632(c, a, bb) \
    c = __builtin_amdgcn_mfma_f32_16x16x32_bf16(a, bb, c, 0, 0, 0)

// Barrier WITHOUT vmcnt drain: per-wave LDS ops (publishes + reads) are
// lgkm-drained, then the waves sync. Global feature prefetches stay in
// flight across it.
__device__ __forceinline__ void wave_barrier() {
    asm volatile("s_waitcnt lgkmcnt(0)" ::: "memory");
    __builtin_amdgcn_s_barrier();
}

// Round-12 variant of the champion (round 7/11) dataflow: one BLOCK = one
// chain, but split over EIGHT waves (wave w owns ONE 16-row tile nt=w:
// 4 MFMAs + ~40 VALU + 5 DS per round). grid 512 -> 2 independent 8-wave
// blocks/CU -> 16 waves/CU = 4 waves/SIMD (vs champion's 2): more, shorter
// compute phases per SIMD to fill barrier-wait and ds_read/MFMA latency;
// publish->barrier-arrive path also shrinks (4 f2bf + 1 ds_write_b64).
// Per-chain arithmetic is BIT-IDENTICAL to round 7: same A-fragments, same
// sequential kt=0..3 MFMA accumulation per tile, same image-derived
// power-of-2 rescale (same values, same order), same ring schedule (duty
// rotates over waves 0-3 only, identical rows), numerator byte-identical
// on waves 0-3.
template <int ISB>
__device__ __forceinline__ void run_chain8(
    const int w, const int lane,
    const float* __restrict__ fb,       // this batch's features (S,L)
    const float* __restrict__ start_t,
    const float* __restrict__ end_t,
    const float* __restrict__ trans,
    short* __restrict__ img,            // LDS [2][LL]
    float* __restrict__ eRing,          // LDS [4][LL]
    const int* __restrict__ lmask,      // LDS [SS]
    float* __restrict__ outv,           // av/bv row (L floats)
    float* __restrict__ oute)           // eFa/eBa slot
{
    const int lo = lane & 15;
    const int hi = lane >> 4;

    // ---- A-fragments for this wave's single tile nt=w (standard mapping:
    //      A slot (hi,j) of k-tile kt <-> k = 32kt+8hi+j, row n = 16w+lo) ----
    // fwd: out[n] = sum_k expT[k][n] u[k];  bwd: out[i] = sum_j expT[i][j] u[j]
    bf16x8 Af[4];
#pragma unroll
    for (int kt = 0; kt < 4; ++kt) {
        bf16x8 fr;
        const int n = 16 * w + lo;
#pragma unroll
        for (int j = 0; j < 8; ++j) {
            const int k = 32 * kt + 8 * hi + j;
            fr[j] = f2bf(__expf(ISB ? trans[n * LL + k] : trans[k * LL + n]));
        }
        Af[kt] = fr;
    }

    // ---- state init (D layout: v[j] = row 16w+4hi+j, cols replicated) ----
    float v[4];
#pragma unroll
    for (int j = 0; j < 4; ++j) {
        const int p = 16 * w + 4 * hi + j;
        v[j] = ISB ? __expf(end_t[p]) : __expf(start_t[p] + fb[p]);
    }

    // ---- bwd: eft_prev prime = exp(f_511) at own positions ----
    f32x4 ep = {1.f, 1.f, 1.f, 1.f};
    if (ISB) {
#pragma unroll
        for (int j = 0; j < 4; ++j)
            ep[j] = __expf(fb[(size_t)511 * LL + 16 * w + 4 * hi + j]);
    }

    // ---- ring prefetch prime (waves 0-3 only, same schedule as champion):
    //      wave w's first duty (round w) serves round w+2 ----
    float2 nxt = make_float2(0.f, 0.f);
    if (w < 4) {
        const int row = ISB ? (508 - w) : (w + 3);
        nxt = *(const float2*)(fb + (size_t)row * LL + 2 * lane);
    }

    wave_barrier();   // ring slots 0/1 + lmask (cooperative fills) visible

    int eacc = 0;

    for (int r = 0; r < 256; ++r) {
        // ---- publish own 4 rows (pre-update state; bwd scaled by eft_prev) ----
        short4 pk;
        pk.x = f2bf(ISB ? v[0] * ep[0] : v[0]);
        pk.y = f2bf(ISB ? v[1] * ep[1] : v[1]);
        pk.z = f2bf(ISB ? v[2] * ep[2] : v[2]);
        pk.w = f2bf(ISB ? v[3] * ep[3] : v[3]);
        short* ib = img + (r & 1) * LL;
        if (lo == 0)
            *(short4*)(ib + 16 * w + 4 * hi) = pk;
        wave_barrier();  // publishes complete + prior-round reads drained

        // ---- full image as B fragments (B slot (hi,j) <-> k=32kt+8hi+j) ----
        bf16x8 Bf[4];
#pragma unroll
        for (int kt = 0; kt < 4; ++kt)
            Bf[kt] = *(const bf16x8*)(ib + 32 * kt + 8 * hi);

        // ---- eft for this round (slot r&3, written 2 rounds ago) ----
        const float* rp = eRing + (r & 3) * LL + 4 * hi;
        f32x4 ec = *(const f32x4*)(rp + 16 * w);

        // ---- ring duty (wave r&3): write slot for round r+2; prefetch ----
        if (w == (r & 3)) {
            *(float2*)(eRing + ((r + 2) & 3) * LL + 2 * lane) =
                make_float2(__expf(nxt.x), __expf(nxt.y));
            const int rowN = ISB ? (504 - r) : (r + 7);  // in [0,512) always
            nxt = *(const float2*)(fb + (size_t)rowN * LL + 2 * lane);
        }

        int mt = lmask[ISB ? (511 - r) : (r + 1)];
        if (!ISB && r == 255) mt = 0;  // fwd dummy round

        // ---- 4 MFMAs, sequential kt accumulation (bit-identical to r7) ----
        f32x4 cc = {0.f, 0.f, 0.f, 0.f};
#pragma unroll
        for (int kt = 0; kt < 4; ++kt)
            MFMA1632(cc, Af[kt], Bf[kt]);

        // ---- epilogue: fwd cand = exp(f_t)*(T^T u); bwd cand = T*pub ----
#pragma unroll
        for (int j = 0; j < 4; ++j) {
            const float cand = ISB ? cc[j] : ec[j] * cc[j];
            v[j] = mt ? cand : v[j];
        }

        // ---- rescale every 8 rounds: identical exponent on all waves,
        //      recomputed from the shared image (exact power of 2) ----
        if ((r & 7) == 7) {
            float s = 0.f;
#pragma unroll
            for (int kt = 0; kt < 4; ++kt)
#pragma unroll
                for (int j = 0; j < 8; ++j) s += bf2f(Bf[kt][j]);
            s += __shfl_xor(s, 16);   // combine hi groups (k-partition)
            s += __shfl_xor(s, 32);
            int ex;
            frexpf(s, &ex);
#pragma unroll
            for (int j = 0; j < 4; ++j) v[j] = ldexpf(v[j], -ex);
            eacc += ex;
        }

        if (ISB) ep = ec;  // eft_prev <- eft_cur
    }

    // ---- export own rows (cols are replicas: lo==0 lanes write) ----
    if (lo == 0)
        *(f32x4*)(outv + 16 * w + 4 * hi) = (f32x4){v[0], v[1], v[2], v[3]};
    if (w == 0 && lane == 0) *oute = (float)eacc;
}

__global__ __launch_bounds__(512, 2) void crf_chain_kernel(
    const float* __restrict__ feats,    // (B,S,L)
    const float* __restrict__ start_t,  // (L)
    const float* __restrict__ end_t,    // (L)
    const float* __restrict__ trans,    // (L,L)
    const int* __restrict__ mask,       // (B,S)
    const int* __restrict__ labels,     // (B,S)
    float* __restrict__ ws)
{
    const int bid = blockIdx.x;
    const int b = bid & 255;
    const int isB = bid >> 8;   // 0 = forward chain, 1 = backward chain
    const int tid = threadIdx.x;
    const int w = tid >> 6;     // wave 0..7
    const int lane = tid & 63;

    __shared__ __align__(16) short img[2 * LL];     // 512 B, dbuf
    __shared__ __align__(16) float eRing[4 * LL];   // 2 KB
    __shared__ int lmask[SS];                       // 2 KB
    __shared__ float nred[4];
    __shared__ int cred[4];

    const float* fb = feats + (size_t)b * SS * LL;

    // ---- cooperative fills (visibility via the barrier inside run_chain8) ----
    lmask[tid] = mask[b * SS + tid];       // 512 threads, one each
    if (tid < 256) {
        const int slot = tid >> 7;          // ring slots 0,1 = rounds 0,1
        const int e = tid & 127;
        const int row = isB ? (510 - slot) : (1 + slot);
        eRing[slot * LL + e] = __expf(fb[(size_t)row * LL + e]);
    }

    float* av = ws;                      // alpha_255 (B,L)
    float* bv = ws + NB * LL;            // beta_255  (B,L)
    float* eFa = ws + 2 * NB * LL;       // fwd exponents (B)
    float* eBa = eFa + NB;               // bwd exponents (B)
    float* lognum = eBa + NB;            // numerator (B)

    if (isB)
        run_chain8<1>(w, lane, fb, start_t, end_t, trans, img, eRing, lmask,
                      bv + b * LL, eBa + b);
    else
        run_chain8<0>(w, lane, fb, start_t, end_t, trans, img, eRing, lmask,
                      av + b * LL, eFa + b);

    // ---- numerator (gold path, fp32 exact), bwd blocks, waves 0-3 only
    //      (byte-identical reduction to the round-7 champion) ----
    if (isB) {
        const int* lb = labels + b * SS;
        const int* mb = mask + b * SS;
        if (w < 4) {
            float term = 0.f;
            int cnt = 0;
#pragma unroll
            for (int q = 0; q < 2; ++q) {
                const int tt = tid + 256 * q;   // tid in [0,256) for w<4
                int l = lb[tt];
                if ((unsigned)l >= LL) l = 0;
                const int m = mb[tt];
                cnt += (m != 0);
                if (tt == 0) {
                    term += start_t[l] + fb[l];
                } else if (m) {
                    int lp = lb[tt - 1];
                    if ((unsigned)lp >= LL) lp = 0;
                    term += trans[lp * LL + l] + fb[(size_t)tt * LL + l];
                }
            }
#pragma unroll
            for (int o = 1; o < 64; o <<= 1) {
                term += __shfl_xor(term, o);
                cnt += __shfl_xor(cnt, o);
            }
            if (lane == 0) { nred[w] = term; cred[w] = cnt; }
        }
        __syncthreads();
        if (tid == 0) {
            const float tot = nred[0] + nred[1] + nred[2] + nred[3];
            const int c = cred[0] + cred[1] + cred[2] + cred[3];
            int sl = c - 1;
            sl = sl < 0 ? 0 : (sl >= SS ? SS - 1 : sl);
            int lt = lb[sl];
            if ((unsigned)lt >= LL) lt = 0;
            lognum[b] = tot + end_t[lt];
        }
    }
}

// Combine: Z = sum_i alpha_255[i]*beta_255[i] * 2^(eF+eB); loss reduce.
__global__ __launch_bounds__(256) void crf_final_kernel(
    const float* __restrict__ ws, const float* __restrict__ conf,
    float* __restrict__ out)
{
    const int tid = threadIdx.x;  // = batch index
    const float* av = ws;
    const float* bv = ws + NB * LL;
    const float* eFa = ws + 2 * NB * LL;
    const float* eBa = eFa + NB;
    const float* ln = eBa + NB;

    const float4* a4 = (const float4*)(av + tid * LL);
    const float4* b4 = (const float4*)(bv + tid * LL);
    float dot = 0.f;
#pragma unroll 8
    for (int k = 0; k < 32; ++k) {
        float4 a = a4[k], bb = b4[k];
        dot += a.x * bb.x + a.y * bb.y + a.z * bb.z + a.w * bb.w;
    }
    float logZ = logf(dot) + 0.69314718055994531f * (eFa[tid] + eBa[tid]);
    float loss = (logZ - ln[tid]) * conf[tid] * (1.0f / NB);

#pragma unroll
    for (int o = 1; o < 64; o <<= 1) loss += __shfl_xor(loss, o);
    __shared__ float red[4];
    if ((tid & 63) == 0) red[tid >> 6] = loss;
    __syncthreads();
    if (tid == 0) out[0] = red[0] + red[1] + red[2] + red[3];
}

extern "C" void kernel_launch(void* const* d_in, const int* in_sizes, int n_in,
                              void* d_out, int out_size, void* d_ws, size_t ws_size,
                              hipStream_t stream) {
    const float* feats  = (const float*)d_in[0];
    const float* startt = (const float*)d_in[1];
    const float* endt   = (const float*)d_in[2];
    const float* trans  = (const float*)d_in[3];
    const float* conf   = (const float*)d_in[4];
    const int*   mask   = (const int*)d_in[5];
    const int*   labels = (const int*)d_in[6];
    float* out = (float*)d_out;
    float* ws = (float*)d_ws;  // needs (2*256*128 + 3*256) floats = ~266 KB

    hipLaunchKernelGGL(crf_chain_kernel, dim3(2 * NB), dim3(512), 0, stream,
                       feats, startt, endt, trans, mask, labels, ws);
    hipLaunchKernelGGL(crf_final_kernel, dim3(1), dim3(256), 0, stream,
                       ws, conf, out);
}